// Round 10
// baseline (3313.140 us; speedup 1.0000x reference)
//
#include <hip/hip_runtime.h>

#define H 1024
#define I_DIM 128
#define O_DIM 128
#define T_DIM 512
#define ALPHA 0.2f
#define NWG 32          // 4 batch-groups x 8 j-slices
#define GSZ 8           // WGs per batch-group

typedef short short8 __attribute__((ext_vector_type(8)));
typedef float f32x4 __attribute__((ext_vector_type(4)));
typedef unsigned long long ull_alias __attribute__((may_alias));

__device__ __forceinline__ unsigned short f2b(float f) {
    union { float f; unsigned u; } x; x.f = f;
    unsigned u = x.u;
    return (unsigned short)((u + 0x7FFFu + ((u >> 16) & 1u)) >> 16);
}
__device__ __forceinline__ float tanh_fast(float x) {
    float e = __expf(2.0f * x);
    return 1.0f - 2.0f * __builtin_amdgcn_rcpf(e + 1.0f);
}
// 8 contiguous f32 -> bf16 fragment (RNE)
__device__ __forceinline__ short8 ld8f(const float* __restrict__ p) {
    const float4 a = *(const float4*)p;
    const float4 b = *(const float4*)(p + 4);
    short8 r;
    r[0]=(short)f2b(a.x); r[1]=(short)f2b(a.y); r[2]=(short)f2b(a.z); r[3]=(short)f2b(a.w);
    r[4]=(short)f2b(b.x); r[5]=(short)f2b(b.y); r[6]=(short)f2b(b.z); r[7]=(short)f2b(b.w);
    return r;
}

// Packed-A layout per batch-group (32 KB = 4096 u64): A[m][k] at u16 offset
//   (k>>5)*512 + ((k&31)>>3)*128 + m*8 + (k&7)
// WG (grp, ji) owns k in [ji*128, ji*128+128) -> contiguous 4 KB at u16 ji*2048.
// Wave w of that WG owns k in [+w*16, +w*16+16) -> contiguous 512 B at +w*256.
// Protocol (R7-proven): data = relaxed agent-scope 8 B atomic stores/loads
// (LLC-coherent point-to-point; no buffer_inv / buffer_wbl2 anywhere); per-wave
// tags in a separate array, published after an explicit vmcnt(0) drain, spun on
// with relaxed loads. 2-parity ring; WAR-safe (consume of t precedes publish of
// t+1, which precedes any overwrite at t+2).
__global__ __launch_bounds__(512, 2) void rnn_kernel(
    const float* __restrict__ x, const float* __restrict__ wi,
    const float* __restrict__ wrec, const float* __restrict__ wout,
    const float* __restrict__ bb, const float* __restrict__ gg,
    const float* __restrict__ h0p, float* __restrict__ out,
    unsigned long long* __restrict__ aG, unsigned int* __restrict__ tagG)
{
    __shared__ unsigned short abuf[32 * 512];   // 32 KB: group's full a_{t-1}
    __shared__ unsigned short aloc[2048];       // 4 KB: own a_t slice, packed
    __shared__ float opart[8 * 256];            // 8 KB: out k-partials (8 waves)

    const int tid  = threadIdx.x;
    const int w    = tid >> 6, lane = tid & 63;  // w in [0,8)
    const int n    = lane & 15, q = lane >> 4;
    const int grp  = blockIdx.x & 3;
    const int ji   = blockIdx.x >> 2;            // [0,8)
    const int j0   = ji * 128;
    const int j    = j0 + w * 16 + n;            // this lane's owned h row
    const int b0   = grp * 16;
    unsigned int* tg = tagG + grp * 128;         // [parity][64] tags

    // ---- register-resident weights (f32 -> bf16, once) ----
    short8 wfr[32];                              // wrec B-frags: B[k][j] = wrec[j][k]
#pragma unroll
    for (int kt = 0; kt < 32; ++kt)
        wfr[kt] = ld8f(&wrec[(size_t)j * H + kt * 32 + q * 8]);

    short8 wifr[4];                              // wi B-frags: B[k][j] = wi[k][j]
#pragma unroll
    for (int kt = 0; kt < 4; ++kt) {
        short8 v;
#pragma unroll
        for (int i = 0; i < 8; ++i)
            v[i] = (short)f2b(wi[(size_t)(kt * 32 + q * 8 + i) * H + j]);
        wifr[kt] = v;
    }
    // wout B-frags: WG covers out cols [ji*16, ji*16+16); wave w covers the
    // k-range [w*128, w*128+128) (4 frags, full 16-col width, no padding).
    short8 wofr[4];
#pragma unroll
    for (int kk = 0; kk < 4; ++kk) {
        short8 v;
        const int kb = w * 128 + kk * 32 + q * 8;
#pragma unroll
        for (int i = 0; i < 8; ++i)
            v[i] = (short)f2b(wout[(size_t)(kb + i) * O_DIM + ji * 16 + n]);
        wofr[kk] = v;
    }

    const float gv = gg[j], bv = bb[j], h00 = h0p[j];
    float hreg[4];
#pragma unroll
    for (int r = 0; r < 4; ++r) hreg[r] = h00;

    const int kl    = w * 16 + n;                // local k in [0,128)
    const int off_l = (kl >> 5) * 512 + ((kl & 31) >> 3) * 128 + (kl & 7);
    const int slot  = ji * 8 + w;                // tag slot in [0,64)

    // publish: 512 B from aloc[w*256..) -> aG (relaxed agent), drain, tag store
    auto publish = [&](int t) {
        asm volatile("" ::: "memory");
        unsigned long long v = *(const ull_alias*)&aloc[w * 256 + lane * 4];
        unsigned long long* dst =
            aG + (size_t)((t & 1) * 4 + grp) * 4096 + (size_t)(ji * 512 + w * 64 + lane);
        __hip_atomic_store(dst, v, __ATOMIC_RELAXED, __HIP_MEMORY_SCOPE_AGENT);
        asm volatile("s_waitcnt vmcnt(0)" ::: "memory");
        if (lane == 0)
            __hip_atomic_store(&tg[(t & 1) * 64 + slot], (unsigned)t,
                               __ATOMIC_RELAXED, __HIP_MEMORY_SCOPE_AGENT);
    };

    auto load_tags = [&](int tv) -> unsigned {
        return __hip_atomic_load(&tg[(tv & 1) * 64 + lane], __ATOMIC_RELAXED,
                                 __HIP_MEMORY_SCOPE_AGENT);
    };

    // consume: wave w pulls chunks [4w, 4w+4) (4 KB) via relaxed agent atomic
    // loads, then ds_write into abuf. 8 u64 staging regs.
    auto consume = [&](int tv) {
        const unsigned long long* src = aG + (size_t)((tv & 1) * 4 + grp) * 4096;
        unsigned long long s0[4], s1[4];
#pragma unroll
        for (int i = 0; i < 4; ++i) {
            const int c = 4 * w + i;
            s0[i] = __hip_atomic_load(src + (size_t)c * 128 + lane,
                                      __ATOMIC_RELAXED, __HIP_MEMORY_SCOPE_AGENT);
            s1[i] = __hip_atomic_load(src + (size_t)c * 128 + 64 + lane,
                                      __ATOMIC_RELAXED, __HIP_MEMORY_SCOPE_AGENT);
        }
        asm volatile("" ::: "memory");
        ull_alias* d64 = (ull_alias*)abuf;
#pragma unroll
        for (int i = 0; i < 4; ++i) {
            const int c = 4 * w + i;
            d64[(size_t)c * 128 + lane]      = s0[i];
            d64[(size_t)c * 128 + 64 + lane] = s1[i];
        }
    };

    // out[:, t, ji*16..+16) from abuf; wave w does k in [w*128, w*128+128)
    auto do_out = [&](int t) {
        f32x4 oa = {0.f, 0.f, 0.f, 0.f};
#pragma unroll
        for (int kk = 0; kk < 4; ++kk) {
            short8 af = *(const short8*)&abuf[(4 * w + kk) * 512 + lane * 8];
            oa = __builtin_amdgcn_mfma_f32_16x16x32_bf16(af, wofr[kk], oa, 0, 0, 0);
        }
#pragma unroll
        for (int r = 0; r < 4; ++r) opart[w * 256 + (4 * q + r) * 16 + n] = oa[r];
        __syncthreads();
        if (tid < 256) {
            float s = 0.f;
#pragma unroll
            for (int wv = 0; wv < 8; ++wv) s += opart[wv * 256 + tid];
            const int m = tid >> 4, c = tid & 15;
            out[((size_t)(b0 + m) * T_DIM + t) * O_DIM + ji * 16 + c] = s;
        }
    };

    // ---- init: stage + publish a0 = g*tanh(h0+b) (batch-broadcast) ----
    {
        unsigned short a0 = f2b(gv * tanh_fast(h00 + bv));
#pragma unroll
        for (int r = 0; r < 4; ++r) aloc[off_l + (4 * q + r) * 8] = a0;
        publish(0);
    }
    unsigned tagv = load_tags(0);                // prime first spin sample

    short8 xfr[4];                               // prefetch x[:,0,:]
#pragma unroll
    for (int kt = 0; kt < 4; ++kt)
        xfr[kt] = ld8f(&x[(size_t)(b0 + n) * T_DIM * I_DIM + kt * 32 + q * 8]);

    for (int t = 1; t < T_DIM; ++t) {
        // x@wi partials: register-only, overlaps stragglers
        f32x4 acc0 = {0.f,0.f,0.f,0.f}, acc1 = {0.f,0.f,0.f,0.f};
        acc0 = __builtin_amdgcn_mfma_f32_16x16x32_bf16(xfr[0], wifr[0], acc0, 0,0,0);
        acc1 = __builtin_amdgcn_mfma_f32_16x16x32_bf16(xfr[1], wifr[1], acc1, 0,0,0);
        acc0 = __builtin_amdgcn_mfma_f32_16x16x32_bf16(xfr[2], wifr[2], acc0, 0,0,0);
        acc1 = __builtin_amdgcn_mfma_f32_16x16x32_bf16(xfr[3], wifr[3], acc1, 0,0,0);

        __syncthreads();          // all waves done with old abuf/opart epoch
        while (!__all(tagv == (unsigned)(t - 1))) {   // spin from primed sample
            __builtin_amdgcn_s_sleep(1);
            tagv = load_tags(t - 1);
        }
        asm volatile("" ::: "memory");
        consume(t - 1);           // relaxed atomic loads -> VGPR -> ds_write
        __syncthreads();          // abuf complete & visible to all waves

        // + a_{t-1} @ wrec^T
#pragma unroll
        for (int kt = 0; kt < 32; kt += 2) {
            short8 a0f = *(const short8*)&abuf[kt * 512 + lane * 8];
            short8 a1f = *(const short8*)&abuf[(kt + 1) * 512 + lane * 8];
            acc0 = __builtin_amdgcn_mfma_f32_16x16x32_bf16(a0f, wfr[kt],     acc0, 0,0,0);
            acc1 = __builtin_amdgcn_mfma_f32_16x16x32_bf16(a1f, wfr[kt + 1], acc1, 0,0,0);
        }

        // h update; stage a_t in aloc (wave-private region), publish
#pragma unroll
        for (int r = 0; r < 4; ++r) {
            float z  = acc0[r] + acc1[r];
            float hv = (1.0f - ALPHA) * hreg[r] + ALPHA * z;
            hreg[r] = hv;
            aloc[off_l + (4 * q + r) * 8] = f2b(gv * tanh_fast(hv + bv));
        }
        publish(t);
        tagv = load_tags(t);      // prime next spin; in flight during xpf/do_out

        // off critical path: x prefetch + out for step t-1
        if (t < T_DIM - 1) {
#pragma unroll
            for (int kt = 0; kt < 4; ++kt)
                xfr[kt] = ld8f(&x[((size_t)(b0 + n) * T_DIM + t) * I_DIM + kt * 32 + q * 8]);
        }
        do_out(t - 1);
    }

    // epilogue: out[:, 511, :] from a_511
    __syncthreads();
    while (!__all(tagv == (unsigned)(T_DIM - 1))) {
        __builtin_amdgcn_s_sleep(1);
        tagv = load_tags(T_DIM - 1);
    }
    asm volatile("" ::: "memory");
    consume(T_DIM - 1);
    __syncthreads();
    do_out(T_DIM - 1);
}

extern "C" void kernel_launch(void* const* d_in, const int* in_sizes, int n_in,
                              void* d_out, int out_size, void* d_ws, size_t ws_size,
                              hipStream_t stream) {
    const float* x    = (const float*)d_in[0];
    const float* wi   = (const float*)d_in[1];
    const float* wrec = (const float*)d_in[2];
    const float* wout = (const float*)d_in[3];
    const float* bb   = (const float*)d_in[4];
    const float* gg   = (const float*)d_in[5];
    const float* h0   = (const float*)d_in[6];
    float* outp = (float*)d_out;

    unsigned long long* aG = (unsigned long long*)d_ws;          // 2x4x32 KB = 256 KB
    unsigned int* tagG = (unsigned int*)((char*)d_ws + 262144);  // 4x2x64 u32 = 2 KB

    hipMemsetAsync(tagG, 0xFF, 4 * 2 * 64 * sizeof(unsigned int), stream);
    hipLaunchKernelGGL(rnn_kernel, dim3(NWG), dim3(512), 0, stream,
                       x, wi, wrec, wout, bb, gg, h0, outp, aG, tagG);
}